// Round 2
// baseline (433.973 us; speedup 1.0000x reference)
//
#include <hip/hip_runtime.h>
#include <cstdint>
#include <cstddef>

// Fastformer on MI355X. R5 pipeline:
//  - transpose-convert weights
//  - k_conv2: bf16-convert Q_seq->buf0 and K_seq->Kstage(=d_out region) in ONE dispatch
//  - k_gemm128 fused dual: Qbf = Qstage@WQ  AND  Khbf = Kstage@WK (2048 blocks)
//    * LDS XOR swizzle: granule g stages global k-octet (g&7)^((g>>3)&7) -> conflict-free b128 reads
//  - q-logits (N=16 MFMA, 64 rows/block so all 256 CUs are busy) -> softmax -> chunked pool -> gq
//  - k-logits fused head-mixing gather + gq folded into B-frag (64 rows/block) -> softmax -> pool -> gk
//  - WPb[b] = WP^T * gk[b,:] ; GEMM3: out = Qbf @ WPb(b) + Qbf

#define B_ 8
#define S_ 2048
#define H_ 16
#define D_ 1024
#define SCALE_ 0.125f
#define BIGNEG_ 1e8f

typedef __attribute__((ext_vector_type(8))) __bf16 bf16x8;
typedef __attribute__((ext_vector_type(4))) float f32x4;

__device__ __forceinline__ unsigned short f2bf(float f) {
  unsigned int u = __float_as_uint(f);
  u += 0x7FFFu + ((u >> 16) & 1u);          // round-to-nearest-even
  return (unsigned short)(u >> 16);
}
__device__ __forceinline__ float bf2f(unsigned short h) {
  return __uint_as_float(((unsigned int)h) << 16);
}

__device__ __forceinline__ void gll16(const void* g, void* l) {
  __builtin_amdgcn_global_load_lds(
      (__attribute__((address_space(1))) void*)(uintptr_t)g,
      (__attribute__((address_space(3))) void*)(uintptr_t)l,
      16, 0, 0);
}

// ---------------- dual elementwise f32 -> bf16 ----------------
__global__ __launch_bounds__(256) void k_conv2(
    const float* __restrict__ in0, unsigned short* __restrict__ out0,
    const float* __restrict__ in1, unsigned short* __restrict__ out1, int n4) {
  int i = blockIdx.x * 256 + threadIdx.x;
  const float* in = in0;
  unsigned short* out = out0;
  if (i >= n4) { i -= n4; in = in1; out = out1; }
  float4 v = ((const float4*)in)[i];
  ushort4 o;
  o.x = f2bf(v.x); o.y = f2bf(v.y); o.z = f2bf(v.z); o.w = f2bf(v.w);
  ((ushort4*)out)[i] = o;
}

// ---------------- transpose + convert, z selects among 3 (K,N)->(N,K) ----------------
__global__ __launch_bounds__(256) void k_transpose3(
    const float* __restrict__ s0, unsigned short* __restrict__ d0,
    const float* __restrict__ s1, unsigned short* __restrict__ d1,
    const float* __restrict__ s2, unsigned short* __restrict__ d2,
    int K, int N) {
  const float* src = blockIdx.z == 0 ? s0 : (blockIdx.z == 1 ? s1 : s2);
  unsigned short* dst = blockIdx.z == 0 ? d0 : (blockIdx.z == 1 ? d1 : d2);
  __shared__ float tile[32][33];
  int n0 = blockIdx.x * 32, k0 = blockIdx.y * 32;
  int tx = threadIdx.x, ty = threadIdx.y;  // (32,8)
#pragma unroll
  for (int i = 0; i < 4; i++) {
    int r = ty + i * 8;
    if (k0 + r < K && n0 + tx < N) tile[r][tx] = src[(size_t)(k0 + r) * N + n0 + tx];
  }
  __syncthreads();
#pragma unroll
  for (int i = 0; i < 4; i++) {
    int rn = ty + i * 8;
    if (n0 + rn < N && k0 + tx < K)
      dst[(size_t)(n0 + rn) * K + k0 + tx] = f2bf(tile[tx][rn]);
  }
}

__global__ __launch_bounds__(256) void k_transpose2(
    const float* __restrict__ s0, unsigned short* __restrict__ d0,
    const float* __restrict__ s1, unsigned short* __restrict__ d1,
    int K, int N) {
  const float* src = blockIdx.z == 0 ? s0 : s1;
  unsigned short* dst = blockIdx.z == 0 ? d0 : d1;
  __shared__ float tile[32][33];
  int n0 = blockIdx.x * 32, k0 = blockIdx.y * 32;
  int tx = threadIdx.x, ty = threadIdx.y;
#pragma unroll
  for (int i = 0; i < 4; i++) {
    int r = ty + i * 8;
    if (k0 + r < K && n0 + tx < N) tile[r][tx] = src[(size_t)(k0 + r) * N + n0 + tx];
  }
  __syncthreads();
#pragma unroll
  for (int i = 0; i < 4; i++) {
    int rn = ty + i * 8;
    if (n0 + rn < N && k0 + tx < K)
      dst[(size_t)(n0 + rn) * K + k0 + tx] = f2bf(tile[tx][rn]);
  }
}

// ---------------- 128x128 bf16 GEMM, BK=64, XOR-swizzled LDS ----------------
// mt < asplit: C = A @ BTa^T -> Cbf ; else (mt-=asplit): C = Aalt @ BTb^T -> Calt
// if bstride: BT += (mt>>4)*bstride (per-batch B). Cf/Res apply to first path only use.
__global__ __launch_bounds__(256) void k_gemm128(
    const unsigned short* __restrict__ A, const unsigned short* __restrict__ Aalt,
    int asplit,
    const unsigned short* __restrict__ BTa, const unsigned short* __restrict__ BTb,
    int bstride,
    unsigned short* __restrict__ Cbf, unsigned short* __restrict__ Calt,
    float* __restrict__ Cf, const unsigned short* __restrict__ Res,
    int N, int K, int ntiles) {
  __shared__ unsigned short lA[128 * 64];
  __shared__ unsigned short lB[128 * 64];
  int t = threadIdx.x;
  int mt = blockIdx.x / ntiles, nt = blockIdx.x - mt * ntiles;
  const unsigned short* BT = BTa;
  unsigned short* Cb = Cbf;
  if (mt >= asplit) { mt -= asplit; A = Aalt; BT = BTb; Cb = Calt; }
  if (bstride) BT += (size_t)(mt >> 4) * bstride;
  int m0 = mt * 128, n0 = nt * 128;
  int lane = t & 63, w = t >> 6;
  int wm = (w >> 1) * 64, wn = (w & 1) * 64;
  int mq = lane & 15, q = lane >> 4;

  f32x4 zero = {0.f, 0.f, 0.f, 0.f};
  f32x4 acc[4][4];
#pragma unroll
  for (int i = 0; i < 4; i++)
#pragma unroll
    for (int j = 0; j < 4; j++) acc[i][j] = zero;

  // staging: granule g = t + p*256; row = g>>3; stages global k-octet (g&7)^(row&7)
  // so that slot layout is conflict-free for b128 fragment reads.
  const unsigned short* gA[4];
  const unsigned short* gB[4];
  unsigned short* pA[4];
  unsigned short* pB[4];
#pragma unroll
  for (int p = 0; p < 4; p++) {
    int g = t + p * 256;
    int row = g >> 3, cg = (g & 7) ^ (row & 7);
    gA[p] = A + (size_t)(m0 + row) * K + cg * 8;
    gB[p] = BT + (size_t)(n0 + row) * K + cg * 8;
    pA[p] = &lA[g * 8];
    pB[p] = &lB[g * 8];
  }

  int xa = mq & 7;  // row&7 for all fragment rows this lane touches
  for (int k0 = 0; k0 < K; k0 += 64) {
#pragma unroll
    for (int p = 0; p < 4; p++) gll16(gA[p] + k0, pA[p]);
#pragma unroll
    for (int p = 0; p < 4; p++) gll16(gB[p] + k0, pB[p]);
    __syncthreads();
#pragma unroll
    for (int kk = 0; kk < 2; kk++) {
      int xo = ((kk * 4 + q) ^ xa) * 8;
      bf16x8 av[4], bv[4];
#pragma unroll
      for (int i = 0; i < 4; i++)
        av[i] = *(const bf16x8*)&lA[(wm + i * 16 + mq) * 64 + xo];
#pragma unroll
      for (int i = 0; i < 4; i++)
        bv[i] = *(const bf16x8*)&lB[(wn + i * 16 + mq) * 64 + xo];
#pragma unroll
      for (int i = 0; i < 4; i++)
#pragma unroll
        for (int j = 0; j < 4; j++)
          acc[i][j] = __builtin_amdgcn_mfma_f32_16x16x32_bf16(av[i], bv[j], acc[i][j], 0, 0, 0);
    }
    __syncthreads();
  }

#pragma unroll
  for (int i = 0; i < 4; i++)
#pragma unroll
    for (int j = 0; j < 4; j++)
#pragma unroll
      for (int r = 0; r < 4; r++) {
        int row = m0 + wm + i * 16 + q * 4 + r;
        int col = n0 + wn + j * 16 + mq;
        size_t o = (size_t)row * N + col;
        float v = acc[i][j][r];
        if (Res) v += bf2f(Res[o]);
        if (Cf) Cf[o] = v;
        if (Cb) Cb[o] = f2bf(v);
      }
}

// ---------------- skinny GEMM N=16: logits with scale+mask (64 rows/block) ----------------
__global__ __launch_bounds__(256) void k_logits16(
    const unsigned short* __restrict__ A,      // (B*S, K) bf16
    const unsigned short* __restrict__ BT16,   // (16, K) bf16
    const float* __restrict__ mask,            // (B*S) f32
    float* __restrict__ outl,                  // (B,16,S) f32
    int K) {
  __shared__ unsigned short lA[64 * 32];
  int t = threadIdx.x;
  int m0 = blockIdx.x * 64;
  int lane = t & 63, w = t >> 6;
  int mq = lane & 15, q = lane >> 4;
  f32x4 acc = {0.f, 0.f, 0.f, 0.f};
  // staging granule: t -> row t>>2 (64 rows), k-octet t&3 (32 K). lane-linear LDS dest.
  const unsigned short* gA = A + (size_t)(m0 + (t >> 2)) * K + (t & 3) * 8;
  unsigned short* pA = &lA[t * 8];
  for (int k0 = 0; k0 < K; k0 += 32) {
    gll16(gA + k0, pA);
    bf16x8 bv = *(const bf16x8*)&BT16[(size_t)mq * K + k0 + q * 8];
    __syncthreads();
    bf16x8 a0 = *(const bf16x8*)&lA[(w * 16 + mq) * 32 + q * 8];
    acc = __builtin_amdgcn_mfma_f32_16x16x32_bf16(a0, bv, acc, 0, 0, 0);
    __syncthreads();
  }
#pragma unroll
  for (int r = 0; r < 4; r++) {
    int row = m0 + w * 16 + q * 4 + r;
    int b = row >> 11, s = row & 2047;
    float v = acc[r] * SCALE_ - (1.0f - mask[row]) * BIGNEG_;
    outl[((size_t)(b * 16 + mq)) * 2048 + s] = v;
  }
}

// ---------------- k-logits with fused head-mixing gather + gq-scaled B (64 rows/block) ----------------
__global__ __launch_bounds__(256) void k_logits16g(
    const unsigned short* __restrict__ Khbf,   // (B,2048,1024) bf16
    const unsigned short* __restrict__ WkT,    // (16,1024) bf16
    const float* __restrict__ gq,              // (B,1024) f32
    const float* __restrict__ mask,            // (B*S) f32
    float* __restrict__ outl) {                // (B,16,S) f32
  __shared__ unsigned short lA[64 * 32];
  int t = threadIdx.x;
  int m0 = blockIdx.x * 64;
  int bb = m0 >> 11;                 // batch (2048 rows per batch)
  int h2 = (m0 >> 7) & 15;           // 128-row chunk within batch == source head
  int half = (m0 >> 6) & 1;          // which 64-row half of the chunk
  int lane = t & 63, w = t >> 6;
  int mq = lane & 15, q = lane >> 4;
  f32x4 acc = {0.f, 0.f, 0.f, 0.f};
  int r0 = half * 64 + (t >> 2);     // chunk-row in [0,128)
  int c0 = t & 3;                    // k-octet in current 32-K slab
  const unsigned short* base = Khbf + (size_t)bb * 2048 * 1024 + h2 * 64;
  const float* gqb = gq + bb * 1024 + h2 * 64;
  unsigned short* pA = &lA[t * 8];
  for (int k0 = 0; k0 < 1024; k0 += 32) {
    int kc0 = k0 + c0 * 8;
    // head-mix gather: QK_flat[m0+r, k] lives at Khbf[bb, 16*r + (k>>6), h2*64 + (k&63)]
    gll16(base + (size_t)(16 * r0 + (kc0 >> 6)) * 1024 + (kc0 & 63), pA);
    int kq = k0 + q * 8;
    bf16x8 wv = *(const bf16x8*)&WkT[(size_t)mq * 1024 + kq];
    float4 g0 = *(const float4*)&gqb[kq & 63];
    float4 g1 = *(const float4*)&gqb[(kq & 63) + 4];
    bf16x8 bv;
    bv[0] = (__bf16)((float)wv[0] * g0.x);
    bv[1] = (__bf16)((float)wv[1] * g0.y);
    bv[2] = (__bf16)((float)wv[2] * g0.z);
    bv[3] = (__bf16)((float)wv[3] * g0.w);
    bv[4] = (__bf16)((float)wv[4] * g1.x);
    bv[5] = (__bf16)((float)wv[5] * g1.y);
    bv[6] = (__bf16)((float)wv[6] * g1.z);
    bv[7] = (__bf16)((float)wv[7] * g1.w);
    __syncthreads();
    bf16x8 a0 = *(const bf16x8*)&lA[(w * 16 + mq) * 32 + q * 8];
    acc = __builtin_amdgcn_mfma_f32_16x16x32_bf16(a0, bv, acc, 0, 0, 0);
    __syncthreads();
  }
#pragma unroll
  for (int r = 0; r < 4; r++) {
    int row = m0 + w * 16 + q * 4 + r;
    int b = row >> 11, s = row & 2047;
    float v = acc[r] * SCALE_ - (1.0f - mask[row]) * BIGNEG_;
    outl[((size_t)(b * 16 + mq)) * 2048 + s] = v;
  }
}

// ---------------- in-place softmax over rows of 2048 ----------------
__global__ __launch_bounds__(256) void k_softmax(float* __restrict__ logits) {
  __shared__ float red[8];
  int t = threadIdx.x;
  int lane = t & 63, w = t >> 6;
  float* lg = logits + (size_t)blockIdx.x * 2048;
  float4 a = ((const float4*)lg)[t];
  float4 b = ((const float4*)lg)[t + 256];
  float mx = fmaxf(fmaxf(fmaxf(a.x, a.y), fmaxf(a.z, a.w)),
                   fmaxf(fmaxf(b.x, b.y), fmaxf(b.z, b.w)));
#pragma unroll
  for (int off = 32; off > 0; off >>= 1) mx = fmaxf(mx, __shfl_down(mx, off, 64));
  if (lane == 0) red[w] = mx;
  __syncthreads();
  mx = fmaxf(fmaxf(red[0], red[1]), fmaxf(red[2], red[3]));
  float4 ea, eb;
  ea.x = expf(a.x - mx); ea.y = expf(a.y - mx); ea.z = expf(a.z - mx); ea.w = expf(a.w - mx);
  eb.x = expf(b.x - mx); eb.y = expf(b.y - mx); eb.z = expf(b.z - mx); eb.w = expf(b.w - mx);
  float ps = ea.x + ea.y + ea.z + ea.w + eb.x + eb.y + eb.z + eb.w;
#pragma unroll
  for (int off = 32; off > 0; off >>= 1) ps += __shfl_down(ps, off, 64);
  if (lane == 0) red[4 + w] = ps;
  __syncthreads();
  float inv = 1.0f / (red[4] + red[5] + red[6] + red[7]);
  ea.x *= inv; ea.y *= inv; ea.z *= inv; ea.w *= inv;
  eb.x *= inv; eb.y *= inv; eb.z *= inv; eb.w *= inv;
  ((float4*)lg)[t] = ea;
  ((float4*)lg)[t + 256] = eb;
}

// ---------------- chunked weighted pool, stage 1 ----------------
__global__ __launch_bounds__(256) void k_poolpart(
    const float* __restrict__ att,             // (B,16,2048) softmaxed
    const unsigned short* __restrict__ X,      // (B,2048,1024) bf16
    float* __restrict__ partial) {             // (B,64,1024) f32
  __shared__ float satt[32 * 16];
  int c = blockIdx.x, b = blockIdx.y;
  int t = threadIdx.x;
  for (int i = t; i < 512; i += 256) {
    int sl = i >> 4, h = i & 15;
    satt[i] = att[(((size_t)b * 16 + h) << 11) + c * 32 + sl];
  }
  __syncthreads();
  int h = t >> 4;
  const ushort4* xp = (const ushort4*)X + ((size_t)b * 2048 + c * 32) * 256 + t;
  float4 acc = {0.f, 0.f, 0.f, 0.f};
#pragma unroll 8
  for (int sl = 0; sl < 32; sl++) {
    float av = satt[sl * 16 + h];
    ushort4 xv = xp[sl * 256];
    acc.x += av * bf2f(xv.x);
    acc.y += av * bf2f(xv.y);
    acc.z += av * bf2f(xv.z);
    acc.w += av * bf2f(xv.w);
  }
  ((float4*)partial)[((size_t)b * 64 + c) * 256 + t] = acc;
}

// ---------------- chunked weighted pool, stage 2 ----------------
__global__ __launch_bounds__(256) void k_poolfin(
    const float* __restrict__ partial,         // (B,64,1024)
    const float* __restrict__ gmul,            // null or (B,1024)
    float* __restrict__ outp) {                // (B,1024)
  int oi = blockIdx.x * 256 + threadIdx.x;
  int b = oi >> 10;
  const float* pp = partial + (size_t)b * 64 * 1024 + (oi & 1023);
  float s = 0.f;
#pragma unroll 8
  for (int c = 0; c < 64; c++) s += pp[(size_t)c * 1024];
  if (gmul) s *= gmul[oi];
  outp[oi] = s;
}

// ---------------- WPb[b][n][k] = WPT[n][k] * gk[b][k] ----------------
__global__ __launch_bounds__(256) void k_wpb(
    const unsigned short* __restrict__ WPT,    // (1024,1024) bf16, N-major
    const float* __restrict__ gk,              // (B,1024)
    unsigned short* __restrict__ WPb) {        // (B,1024,1024) bf16
  int i = blockIdx.x * 256 + threadIdx.x;
  int flat4 = i * 4;
  int b = flat4 >> 20;
  int rem = flat4 & 1048575;
  int k = rem & 1023;
  ushort4 wv = *(const ushort4*)&WPT[rem];
  float4 gv = *(const float4*)&gk[b * 1024 + k];
  ushort4 o;
  o.x = f2bf(bf2f(wv.x) * gv.x);
  o.y = f2bf(bf2f(wv.y) * gv.y);
  o.z = f2bf(bf2f(wv.z) * gv.z);
  o.w = f2bf(bf2f(wv.w) * gv.w);
  *(ushort4*)&WPb[flat4] = o;
}

extern "C" void kernel_launch(void* const* d_in, const int* in_sizes, int n_in,
                              void* d_out, int out_size, void* d_ws, size_t ws_size,
                              hipStream_t stream) {
  const float* Qseq  = (const float*)d_in[0];
  const float* Kseq  = (const float*)d_in[1];
  const float* Qmask = (const float*)d_in[2];
  const float* Kmask = (const float*)d_in[3];
  const float* WQ    = (const float*)d_in[4];
  const float* WK    = (const float*)d_in[5];
  const float* Wq    = (const float*)d_in[6];
  const float* Wk    = (const float*)d_in[7];
  const float* WP    = (const float*)d_in[8];
  float* out = (float*)d_out;

  const size_t SD = (size_t)B_ * S_ * D_;  // 16,777,216
  unsigned short* Qbf  = (unsigned short*)d_ws;
  unsigned short* Khbf = Qbf + SD;
  unsigned short* buf0 = Khbf + SD;           // Q conv staging; later partial(2MB)+WPb(16MB)
  unsigned short* WQT  = buf0 + SD;
  unsigned short* WKT  = WQT + (size_t)D_ * D_;
  unsigned short* WPT  = WKT + (size_t)D_ * D_;
  unsigned short* WqT  = WPT + (size_t)D_ * D_;
  unsigned short* WkT  = WqT + (size_t)H_ * D_;
  float* ql = (float*)(WkT + (size_t)H_ * D_);
  float* kl = ql + (size_t)B_ * H_ * S_;
  float* gq = kl + (size_t)B_ * H_ * S_;
  float* gk = gq + (size_t)B_ * D_;
  float* partial = (float*)buf0;                            // 2 MB
  unsigned short* WPb = buf0 + 2 * 1024 * 1024;             // 16 MB
  unsigned short* Kstage = (unsigned short*)d_out;          // 32 MB of the 64 MB f32 out buffer

  dim3 blk256(256);
  dim3 tblk(32, 8);
  int n4 = (int)(SD / 4);

  // weight conversions
  k_transpose3<<<dim3(32, 32, 3), tblk, 0, stream>>>(WQ, WQT, WK, WKT, WP, WPT, D_, D_);
  k_transpose2<<<dim3(1, 32, 2), tblk, 0, stream>>>(Wq, WqT, Wk, WkT, D_, H_);

  // convert both activations in one dispatch
  k_conv2<<<dim3(2 * ((n4 + 255) / 256)), blk256, 0, stream>>>(Qseq, buf0, Kseq, Kstage, n4);

  // fused GEMM1+GEMM2: Qbf = Qstage@WQ ; Khbf = Kstage@WK
  k_gemm128<<<dim3(2048), blk256, 0, stream>>>(buf0, Kstage, 128, WQT, WKT, 0,
                                               Qbf, Khbf, (float*)nullptr,
                                               (const unsigned short*)nullptr, D_, D_, 8);

  // q attention -> gq
  k_logits16<<<dim3(256), blk256, 0, stream>>>(Qbf, WqT, Qmask, ql, D_);
  k_softmax<<<dim3(128), blk256, 0, stream>>>(ql);
  k_poolpart<<<dim3(64, 8), blk256, 0, stream>>>(ql, Qbf, partial);
  k_poolfin<<<dim3(32), blk256, 0, stream>>>(partial, (const float*)nullptr, gq);

  // k attention (fused gather over head-mixed QK_flat) -> gk
  k_logits16g<<<dim3(256), blk256, 0, stream>>>(Khbf, WkT, gq, Kmask, kl);
  k_softmax<<<dim3(128), blk256, 0, stream>>>(kl);
  k_poolpart<<<dim3(64, 8), blk256, 0, stream>>>(kl, Khbf, partial);
  k_poolfin<<<dim3(32), blk256, 0, stream>>>(partial, gq, gk);

  // final: out = Qbf @ (WP .* gk[b]) + Qbf   (overwrites Kstage region — no longer read)
  k_wpb<<<dim3(8192), blk256, 0, stream>>>(WPT, gk, WPb);
  k_gemm128<<<dim3(1024), blk256, 0, stream>>>(Qbf, Qbf, 1 << 30, WPb, WPb, 1 << 20,
                                               (unsigned short*)nullptr, (unsigned short*)nullptr,
                                               out, Qbf, D_, D_, 8);
}

// Round 3
// 390.057 us; speedup vs baseline: 1.1126x; 1.1126x over previous
//
#include <hip/hip_runtime.h>
#include <cstdint>
#include <cstddef>

// Fastformer on MI355X. R6 pipeline:
//  - k_gemm256: 256x256 tile, BK=32, double-buffered LDS (64KB), counted-vmcnt
//    software pipeline (raw s_barrier, vmcnt(4) steady-state, never 0 in loop),
//    setprio around MFMA cluster, granule-XOR swizzled LDS (0-conflict family),
//    XCD-chunked block swizzle. Used for BOTH the dual GEMM1+2 and final GEMM3.
//  - rest of pipeline unchanged from verified R5.

#define B_ 8
#define S_ 2048
#define H_ 16
#define D_ 1024
#define SCALE_ 0.125f
#define BIGNEG_ 1e8f

typedef __attribute__((ext_vector_type(8))) __bf16 bf16x8;
typedef __attribute__((ext_vector_type(4))) float f32x4;

__device__ __forceinline__ unsigned short f2bf(float f) {
  unsigned int u = __float_as_uint(f);
  u += 0x7FFFu + ((u >> 16) & 1u);          // round-to-nearest-even
  return (unsigned short)(u >> 16);
}
__device__ __forceinline__ float bf2f(unsigned short h) {
  return __uint_as_float(((unsigned int)h) << 16);
}

__device__ __forceinline__ void gll16(const void* g, void* l) {
  __builtin_amdgcn_global_load_lds(
      (__attribute__((address_space(1))) void*)(uintptr_t)g,
      (__attribute__((address_space(3))) void*)(uintptr_t)l,
      16, 0, 0);
}

// ---------------- dual elementwise f32 -> bf16 ----------------
__global__ __launch_bounds__(256) void k_conv2(
    const float* __restrict__ in0, unsigned short* __restrict__ out0,
    const float* __restrict__ in1, unsigned short* __restrict__ out1, int n4) {
  int i = blockIdx.x * 256 + threadIdx.x;
  const float* in = in0;
  unsigned short* out = out0;
  if (i >= n4) { i -= n4; in = in1; out = out1; }
  float4 v = ((const float4*)in)[i];
  ushort4 o;
  o.x = f2bf(v.x); o.y = f2bf(v.y); o.z = f2bf(v.z); o.w = f2bf(v.w);
  ((ushort4*)out)[i] = o;
}

// ---------------- transpose + convert, z selects among 3 (K,N)->(N,K) ----------------
__global__ __launch_bounds__(256) void k_transpose3(
    const float* __restrict__ s0, unsigned short* __restrict__ d0,
    const float* __restrict__ s1, unsigned short* __restrict__ d1,
    const float* __restrict__ s2, unsigned short* __restrict__ d2,
    int K, int N) {
  const float* src = blockIdx.z == 0 ? s0 : (blockIdx.z == 1 ? s1 : s2);
  unsigned short* dst = blockIdx.z == 0 ? d0 : (blockIdx.z == 1 ? d1 : d2);
  __shared__ float tile[32][33];
  int n0 = blockIdx.x * 32, k0 = blockIdx.y * 32;
  int tx = threadIdx.x, ty = threadIdx.y;  // (32,8)
#pragma unroll
  for (int i = 0; i < 4; i++) {
    int r = ty + i * 8;
    if (k0 + r < K && n0 + tx < N) tile[r][tx] = src[(size_t)(k0 + r) * N + n0 + tx];
  }
  __syncthreads();
#pragma unroll
  for (int i = 0; i < 4; i++) {
    int rn = ty + i * 8;
    if (n0 + rn < N && k0 + tx < K)
      dst[(size_t)(n0 + rn) * K + k0 + tx] = f2bf(tile[tx][rn]);
  }
}

__global__ __launch_bounds__(256) void k_transpose2(
    const float* __restrict__ s0, unsigned short* __restrict__ d0,
    const float* __restrict__ s1, unsigned short* __restrict__ d1,
    int K, int N) {
  const float* src = blockIdx.z == 0 ? s0 : s1;
  unsigned short* dst = blockIdx.z == 0 ? d0 : d1;
  __shared__ float tile[32][33];
  int n0 = blockIdx.x * 32, k0 = blockIdx.y * 32;
  int tx = threadIdx.x, ty = threadIdx.y;
#pragma unroll
  for (int i = 0; i < 4; i++) {
    int r = ty + i * 8;
    if (k0 + r < K && n0 + tx < N) tile[r][tx] = src[(size_t)(k0 + r) * N + n0 + tx];
  }
  __syncthreads();
#pragma unroll
  for (int i = 0; i < 4; i++) {
    int rn = ty + i * 8;
    if (n0 + rn < N && k0 + tx < K)
      dst[(size_t)(n0 + rn) * K + k0 + tx] = f2bf(tile[tx][rn]);
  }
}

// ---------------- 256x256 bf16 GEMM, BK=32, dbuf + counted vmcnt pipeline ------
// Tiles: A[256][32], B^T[256][32] per K-step, stored as [128 rowpair][8 granule]
// with granule slot = ((r&1)*4 + oct) ^ ((r>>1)&7)  (same byte pattern family as
// the verified 128^2 kernel: 128B row-stride, 8 16B slots, XOR by low row bits ->
// measured 0 bank conflicts).
// Pipeline per iteration (NT = K/32):
//   vmcnt(4) [tile it landed; tile it+1 in flight] ; s_barrier
//   ds_read 12 b128 frags ; lgkmcnt(0) ; s_barrier   [buf consumed]
//   stage tile it+2 into this buf (4 x global_load_lds, stay in flight)
//   setprio(1) ; 32 MFMA ; setprio(0)
// mt < asplit: C = A@BTa^T -> Cbf ; else: C = Aalt@BTb^T -> Calt.
// bstride: BT += (mt>>bshift)*bstride. Cf/Res: f32 out + bf16 residual add.
__global__ __launch_bounds__(512, 2) void k_gemm256(
    const unsigned short* __restrict__ A, const unsigned short* __restrict__ Aalt,
    int asplit,
    const unsigned short* __restrict__ BTa, const unsigned short* __restrict__ BTb,
    int bstride, int bshift,
    unsigned short* __restrict__ Cbf, unsigned short* __restrict__ Calt,
    float* __restrict__ Cf, const unsigned short* __restrict__ Res,
    int N, int K, int ntiles) {
  __shared__ unsigned short lds[32768];  // 2 bufs x (A 8192 + B 8192 shorts) = 64KB
  int t = threadIdx.x;
  // XCD-chunked swizzle: consecutive logical tiles land on one XCD's L2.
  int lid = (blockIdx.x & 7) * ((int)gridDim.x >> 3) + (blockIdx.x >> 3);
  int mt = lid / ntiles, nt = lid - mt * ntiles;
  const unsigned short* BT = BTa;
  unsigned short* Cb = Cbf;
  if (mt >= asplit) { mt -= asplit; A = Aalt; BT = BTb; Cb = Calt; }
  if (bstride) BT += (size_t)(mt >> bshift) * (size_t)bstride;
  int m0 = mt * 256, n0 = nt * 256;
  int lane = t & 63, w = t >> 6;
  int wr = (w >> 2) * 128;   // wave row base within A tile (2 M-waves)
  int wc = (w & 3) * 64;     // wave col base within B tile (4 N-waves)
  int mq = lane & 15, q = lane >> 4;

  f32x4 zero = {0.f, 0.f, 0.f, 0.f};
  f32x4 acc[8][4];
#pragma unroll
  for (int i = 0; i < 8; i++)
#pragma unroll
    for (int j = 0; j < 4; j++) acc[i][j] = zero;

  // staging: granule g = t + p*512 in [0,1024): row2 = g>>3, slot = g&7,
  // pre = slot ^ (row2&7) -> global (r = row2*2 + (pre>>2), oct = pre&3).
  const unsigned short* gA[2];
  const unsigned short* gB[2];
  int oA[2], oB[2];
#pragma unroll
  for (int p = 0; p < 2; p++) {
    int g = t + p * 512;
    int row2 = g >> 3, pre = (g & 7) ^ (row2 & 7);
    int r = row2 * 2 + (pre >> 2), oct = pre & 3;
    gA[p] = A + (size_t)(m0 + r) * K + oct * 8;
    gB[p] = BT + (size_t)(n0 + r) * K + oct * 8;
    oA[p] = g * 8;
    oB[p] = 8192 + g * 8;
  }

  // fragment read addressing: slot = ((mq&1)*4 + q) ^ ((mq>>1)&7), row2 varies.
  int sA8 = ((((mq & 1) << 2) | q) ^ (mq >> 1)) * 8;
  int ra = (wr >> 1) + (mq >> 1);
  int rb = (wc >> 1) + (mq >> 1);

  int NT = K >> 5;  // 32 for K=1024
  // prologue: stage tiles 0 (buf0) and 1 (buf1) — 8 loads outstanding
#pragma unroll
  for (int p = 0; p < 2; p++) gll16(gA[p], &lds[oA[p]]);
#pragma unroll
  for (int p = 0; p < 2; p++) gll16(gB[p], &lds[oB[p]]);
#pragma unroll
  for (int p = 0; p < 2; p++) gll16(gA[p] + 32, &lds[16384 + oA[p]]);
#pragma unroll
  for (int p = 0; p < 2; p++) gll16(gB[p] + 32, &lds[16384 + oB[p]]);

  for (int it = 0; it < NT; ++it) {
    int lbase = (it & 1) << 14;  // cur*16384
    if (it < NT - 1) {
      asm volatile("s_waitcnt vmcnt(4)" ::: "memory");
    } else {
      asm volatile("s_waitcnt vmcnt(0)" ::: "memory");
    }
    __builtin_amdgcn_s_barrier();
    __builtin_amdgcn_sched_barrier(0);

    const unsigned short* la = &lds[lbase];
    const unsigned short* lb = &lds[lbase + 8192];
    bf16x8 av[8], bv[4];
#pragma unroll
    for (int i = 0; i < 8; i++)
      av[i] = *(const bf16x8*)&la[(ra + i * 8) * 64 + sA8];
#pragma unroll
    for (int j = 0; j < 4; j++)
      bv[j] = *(const bf16x8*)&lb[(rb + j * 8) * 64 + sA8];
    asm volatile("s_waitcnt lgkmcnt(0)" ::: "memory");
    __builtin_amdgcn_sched_barrier(0);
    __builtin_amdgcn_s_barrier();     // buf[cur] fully consumed by all waves
    __builtin_amdgcn_sched_barrier(0);

    if (it + 2 < NT) {                // stage tile it+2 into buf[cur]
      int k0 = (it + 2) * 32;
#pragma unroll
      for (int p = 0; p < 2; p++) gll16(gA[p] + k0, &lds[lbase + oA[p]]);
#pragma unroll
      for (int p = 0; p < 2; p++) gll16(gB[p] + k0, &lds[lbase + oB[p]]);
    }

    __builtin_amdgcn_s_setprio(1);
#pragma unroll
    for (int i = 0; i < 8; i++)
#pragma unroll
      for (int j = 0; j < 4; j++)
        acc[i][j] = __builtin_amdgcn_mfma_f32_16x16x32_bf16(av[i], bv[j], acc[i][j], 0, 0, 0);
    __builtin_amdgcn_s_setprio(0);
  }

#pragma unroll
  for (int i = 0; i < 8; i++)
#pragma unroll
    for (int j = 0; j < 4; j++)
#pragma unroll
      for (int r = 0; r < 4; r++) {
        int row = m0 + wr + i * 16 + q * 4 + r;
        int col = n0 + wc + j * 16 + mq;
        size_t o = (size_t)row * N + col;
        float v = acc[i][j][r];
        if (Res) v += bf2f(Res[o]);
        if (Cf) Cf[o] = v;
        if (Cb) Cb[o] = f2bf(v);
      }
}

// ---------------- skinny GEMM N=16: logits with scale+mask (64 rows/block) ----------------
__global__ __launch_bounds__(256) void k_logits16(
    const unsigned short* __restrict__ A,      // (B*S, K) bf16
    const unsigned short* __restrict__ BT16,   // (16, K) bf16
    const float* __restrict__ mask,            // (B*S) f32
    float* __restrict__ outl,                  // (B,16,S) f32
    int K) {
  __shared__ unsigned short lA[64 * 32];
  int t = threadIdx.x;
  int m0 = blockIdx.x * 64;
  int lane = t & 63, w = t >> 6;
  int mq = lane & 15, q = lane >> 4;
  f32x4 acc = {0.f, 0.f, 0.f, 0.f};
  const unsigned short* gA = A + (size_t)(m0 + (t >> 2)) * K + (t & 3) * 8;
  unsigned short* pA = &lA[t * 8];
  for (int k0 = 0; k0 < K; k0 += 32) {
    gll16(gA + k0, pA);
    bf16x8 bv = *(const bf16x8*)&BT16[(size_t)mq * K + k0 + q * 8];
    __syncthreads();
    bf16x8 a0 = *(const bf16x8*)&lA[(w * 16 + mq) * 32 + q * 8];
    acc = __builtin_amdgcn_mfma_f32_16x16x32_bf16(a0, bv, acc, 0, 0, 0);
    __syncthreads();
  }
#pragma unroll
  for (int r = 0; r < 4; r++) {
    int row = m0 + w * 16 + q * 4 + r;
    int b = row >> 11, s = row & 2047;
    float v = acc[r] * SCALE_ - (1.0f - mask[row]) * BIGNEG_;
    outl[((size_t)(b * 16 + mq)) * 2048 + s] = v;
  }
}

// ---------------- k-logits with fused head-mixing gather + gq-scaled B (64 rows/block) ----------------
__global__ __launch_bounds__(256) void k_logits16g(
    const unsigned short* __restrict__ Khbf,   // (B,2048,1024) bf16
    const unsigned short* __restrict__ WkT,    // (16,1024) bf16
    const float* __restrict__ gq,              // (B,1024) f32
    const float* __restrict__ mask,            // (B*S) f32
    float* __restrict__ outl) {                // (B,16,S) f32
  __shared__ unsigned short lA[64 * 32];
  int t = threadIdx.x;
  int m0 = blockIdx.x * 64;
  int bb = m0 >> 11;
  int h2 = (m0 >> 7) & 15;
  int half = (m0 >> 6) & 1;
  int lane = t & 63, w = t >> 6;
  int mq = lane & 15, q = lane >> 4;
  f32x4 acc = {0.f, 0.f, 0.f, 0.f};
  int r0 = half * 64 + (t >> 2);
  int c0 = t & 3;
  const unsigned short* base = Khbf + (size_t)bb * 2048 * 1024 + h2 * 64;
  const float* gqb = gq + bb * 1024 + h2 * 64;
  unsigned short* pA = &lA[t * 8];
  for (int k0 = 0; k0 < 1024; k0 += 32) {
    int kc0 = k0 + c0 * 8;
    gll16(base + (size_t)(16 * r0 + (kc0 >> 6)) * 1024 + (kc0 & 63), pA);
    int kq = k0 + q * 8;
    bf16x8 wv = *(const bf16x8*)&WkT[(size_t)mq * 1024 + kq];
    float4 g0 = *(const float4*)&gqb[kq & 63];
    float4 g1 = *(const float4*)&gqb[(kq & 63) + 4];
    bf16x8 bv;
    bv[0] = (__bf16)((float)wv[0] * g0.x);
    bv[1] = (__bf16)((float)wv[1] * g0.y);
    bv[2] = (__bf16)((float)wv[2] * g0.z);
    bv[3] = (__bf16)((float)wv[3] * g0.w);
    bv[4] = (__bf16)((float)wv[4] * g1.x);
    bv[5] = (__bf16)((float)wv[5] * g1.y);
    bv[6] = (__bf16)((float)wv[6] * g1.z);
    bv[7] = (__bf16)((float)wv[7] * g1.w);
    __syncthreads();
    bf16x8 a0 = *(const bf16x8*)&lA[(w * 16 + mq) * 32 + q * 8];
    acc = __builtin_amdgcn_mfma_f32_16x16x32_bf16(a0, bv, acc, 0, 0, 0);
    __syncthreads();
  }
#pragma unroll
  for (int r = 0; r < 4; r++) {
    int row = m0 + w * 16 + q * 4 + r;
    int b = row >> 11, s = row & 2047;
    float v = acc[r] * SCALE_ - (1.0f - mask[row]) * BIGNEG_;
    outl[((size_t)(b * 16 + mq)) * 2048 + s] = v;
  }
}

// ---------------- in-place softmax over rows of 2048 ----------------
__global__ __launch_bounds__(256) void k_softmax(float* __restrict__ logits) {
  __shared__ float red[8];
  int t = threadIdx.x;
  int lane = t & 63, w = t >> 6;
  float* lg = logits + (size_t)blockIdx.x * 2048;
  float4 a = ((const float4*)lg)[t];
  float4 b = ((const float4*)lg)[t + 256];
  float mx = fmaxf(fmaxf(fmaxf(a.x, a.y), fmaxf(a.z, a.w)),
                   fmaxf(fmaxf(b.x, b.y), fmaxf(b.z, b.w)));
#pragma unroll
  for (int off = 32; off > 0; off >>= 1) mx = fmaxf(mx, __shfl_down(mx, off, 64));
  if (lane == 0) red[w] = mx;
  __syncthreads();
  mx = fmaxf(fmaxf(red[0], red[1]), fmaxf(red[2], red[3]));
  float4 ea, eb;
  ea.x = expf(a.x - mx); ea.y = expf(a.y - mx); ea.z = expf(a.z - mx); ea.w = expf(a.w - mx);
  eb.x = expf(b.x - mx); eb.y = expf(b.y - mx); eb.z = expf(b.z - mx); eb.w = expf(b.w - mx);
  float ps = ea.x + ea.y + ea.z + ea.w + eb.x + eb.y + eb.z + eb.w;
#pragma unroll
  for (int off = 32; off > 0; off >>= 1) ps += __shfl_down(ps, off, 64);
  if (lane == 0) red[4 + w] = ps;
  __syncthreads();
  float inv = 1.0f / (red[4] + red[5] + red[6] + red[7]);
  ea.x *= inv; ea.y *= inv; ea.z *= inv; ea.w *= inv;
  eb.x *= inv; eb.y *= inv; eb.z *= inv; eb.w *= inv;
  ((float4*)lg)[t] = ea;
  ((float4*)lg)[t + 256] = eb;
}

// ---------------- chunked weighted pool, stage 1 ----------------
__global__ __launch_bounds__(256) void k_poolpart(
    const float* __restrict__ att,             // (B,16,2048) softmaxed
    const unsigned short* __restrict__ X,      // (B,2048,1024) bf16
    float* __restrict__ partial) {             // (B,64,1024) f32
  __shared__ float satt[32 * 16];
  int c = blockIdx.x, b = blockIdx.y;
  int t = threadIdx.x;
  for (int i = t; i < 512; i += 256) {
    int sl = i >> 4, h = i & 15;
    satt[i] = att[(((size_t)b * 16 + h) << 11) + c * 32 + sl];
  }
  __syncthreads();
  int h = t >> 4;
  const ushort4* xp = (const ushort4*)X + ((size_t)b * 2048 + c * 32) * 256 + t;
  float4 acc = {0.f, 0.f, 0.f, 0.f};
#pragma unroll 8
  for (int sl = 0; sl < 32; sl++) {
    float av = satt[sl * 16 + h];
    ushort4 xv = xp[sl * 256];
    acc.x += av * bf2f(xv.x);
    acc.y += av * bf2f(xv.y);
    acc.z += av * bf2f(xv.z);
    acc.w += av * bf2f(xv.w);
  }
  ((float4*)partial)[((size_t)b * 64 + c) * 256 + t] = acc;
}

// ---------------- chunked weighted pool, stage 2 ----------------
__global__ __launch_bounds__(256) void k_poolfin(
    const float* __restrict__ partial,         // (B,64,1024)
    const float* __restrict__ gmul,            // null or (B,1024)
    float* __restrict__ outp) {                // (B,1024)
  int oi = blockIdx.x * 256 + threadIdx.x;
  int b = oi >> 10;
  const float* pp = partial + (size_t)b * 64 * 1024 + (oi & 1023);
  float s = 0.f;
#pragma unroll 8
  for (int c = 0; c < 64; c++) s += pp[(size_t)c * 1024];
  if (gmul) s *= gmul[oi];
  outp[oi] = s;
}

// ---------------- WPb[b][n][k] = WPT[n][k] * gk[b][k] ----------------
__global__ __launch_bounds__(256) void k_wpb(
    const unsigned short* __restrict__ WPT,    // (1024,1024) bf16, N-major
    const float* __restrict__ gk,              // (B,1024)
    unsigned short* __restrict__ WPb) {        // (B,1024,1024) bf16
  int i = blockIdx.x * 256 + threadIdx.x;
  int flat4 = i * 4;
  int b = flat4 >> 20;
  int rem = flat4 & 1048575;
  int k = rem & 1023;
  ushort4 wv = *(const ushort4*)&WPT[rem];
  float4 gv = *(const float4*)&gk[b * 1024 + k];
  ushort4 o;
  o.x = f2bf(bf2f(wv.x) * gv.x);
  o.y = f2bf(bf2f(wv.y) * gv.y);
  o.z = f2bf(bf2f(wv.z) * gv.z);
  o.w = f2bf(bf2f(wv.w) * gv.w);
  *(ushort4*)&WPb[flat4] = o;
}

extern "C" void kernel_launch(void* const* d_in, const int* in_sizes, int n_in,
                              void* d_out, int out_size, void* d_ws, size_t ws_size,
                              hipStream_t stream) {
  const float* Qseq  = (const float*)d_in[0];
  const float* Kseq  = (const float*)d_in[1];
  const float* Qmask = (const float*)d_in[2];
  const float* Kmask = (const float*)d_in[3];
  const float* WQ    = (const float*)d_in[4];
  const float* WK    = (const float*)d_in[5];
  const float* Wq    = (const float*)d_in[6];
  const float* Wk    = (const float*)d_in[7];
  const float* WP    = (const float*)d_in[8];
  float* out = (float*)d_out;

  const size_t SD = (size_t)B_ * S_ * D_;  // 16,777,216
  unsigned short* Qbf  = (unsigned short*)d_ws;
  unsigned short* Khbf = Qbf + SD;
  unsigned short* buf0 = Khbf + SD;           // Q conv staging; later partial(2MB)+WPb(16MB)
  unsigned short* WQT  = buf0 + SD;
  unsigned short* WKT  = WQT + (size_t)D_ * D_;
  unsigned short* WPT  = WKT + (size_t)D_ * D_;
  unsigned short* WqT  = WPT + (size_t)D_ * D_;
  unsigned short* WkT  = WqT + (size_t)H_ * D_;
  float* ql = (float*)(WkT + (size_t)H_ * D_);
  float* kl = ql + (size_t)B_ * H_ * S_;
  float* gq = kl + (size_t)B_ * H_ * S_;
  float* gk = gq + (size_t)B_ * D_;
  float* partial = (float*)buf0;                            // 2 MB
  unsigned short* WPb = buf0 + 2 * 1024 * 1024;             // 16 MB
  unsigned short* Kstage = (unsigned short*)d_out;          // 32 MB of the 64 MB f32 out buffer

  dim3 blk256(256);
  dim3 blk512(512);
  dim3 tblk(32, 8);
  int n4 = (int)(SD / 4);

  // weight conversions
  k_transpose3<<<dim3(32, 32, 3), tblk, 0, stream>>>(WQ, WQT, WK, WKT, WP, WPT, D_, D_);
  k_transpose2<<<dim3(1, 32, 2), tblk, 0, stream>>>(Wq, WqT, Wk, WkT, D_, H_);

  // convert both activations in one dispatch
  k_conv2<<<dim3(2 * ((n4 + 255) / 256)), blk256, 0, stream>>>(Qseq, buf0, Kseq, Kstage, n4);

  // fused GEMM1+GEMM2: Qbf = Qstage@WQ ; Khbf = Kstage@WK   (64 mtiles per half, 4 ntiles)
  k_gemm256<<<dim3(512), blk512, 0, stream>>>(buf0, Kstage, 64, WQT, WKT, 0, 0,
                                              Qbf, Khbf, (float*)nullptr,
                                              (const unsigned short*)nullptr, D_, D_, 4);

  // q attention -> gq
  k_logits16<<<dim3(256), blk256, 0, stream>>>(Qbf, WqT, Qmask, ql, D_);
  k_softmax<<<dim3(128), blk256, 0, stream>>>(ql);
  k_poolpart<<<dim3(64, 8), blk256, 0, stream>>>(ql, Qbf, partial);
  k_poolfin<<<dim3(32), blk256, 0, stream>>>(partial, (const float*)nullptr, gq);

  // k attention (fused gather over head-mixed QK_flat) -> gk
  k_logits16g<<<dim3(256), blk256, 0, stream>>>(Khbf, WkT, gq, Kmask, kl);
  k_softmax<<<dim3(128), blk256, 0, stream>>>(kl);
  k_poolpart<<<dim3(64, 8), blk256, 0, stream>>>(kl, Khbf, partial);
  k_poolfin<<<dim3(32), blk256, 0, stream>>>(partial, gq, gk);

  // final: out = Qbf @ (WP .* gk[b]) + Qbf   (overwrites Kstage region — no longer read)
  k_wpb<<<dim3(8192), blk256, 0, stream>>>(WPT, gk, WPb);
  k_gemm256<<<dim3(256), blk512, 0, stream>>>(Qbf, Qbf, 1 << 30, WPb, WPb, 1 << 20, 3,
                                              (unsigned short*)nullptr, (unsigned short*)nullptr,
                                              out, Qbf, D_, D_, 4);
}

// Round 4
// 387.566 us; speedup vs baseline: 1.1197x; 1.0064x over previous
//
#include <hip/hip_runtime.h>
#include <cstdint>
#include <cstddef>

// Fastformer on MI355X. R7 pipeline:
//  - k_gemm256: 256x256 tile, BK=32, double-buffered LDS (64KB), counted-vmcnt
//    pipeline + 2-PHASE ds_read/MFMA interleave (lgkmcnt(4) mid-wait), setprio,
//    granule-XOR swizzled LDS (0-conflict, verified), XCD-chunked block swizzle.
//  - rest of pipeline unchanged from verified R6.

#define B_ 8
#define S_ 2048
#define H_ 16
#define D_ 1024
#define SCALE_ 0.125f
#define BIGNEG_ 1e8f

typedef __attribute__((ext_vector_type(8))) __bf16 bf16x8;
typedef __attribute__((ext_vector_type(4))) float f32x4;

__device__ __forceinline__ unsigned short f2bf(float f) {
  unsigned int u = __float_as_uint(f);
  u += 0x7FFFu + ((u >> 16) & 1u);          // round-to-nearest-even
  return (unsigned short)(u >> 16);
}
__device__ __forceinline__ float bf2f(unsigned short h) {
  return __uint_as_float(((unsigned int)h) << 16);
}

__device__ __forceinline__ void gll16(const void* g, void* l) {
  __builtin_amdgcn_global_load_lds(
      (__attribute__((address_space(1))) void*)(uintptr_t)g,
      (__attribute__((address_space(3))) void*)(uintptr_t)l,
      16, 0, 0);
}

// ---------------- dual elementwise f32 -> bf16 ----------------
__global__ __launch_bounds__(256) void k_conv2(
    const float* __restrict__ in0, unsigned short* __restrict__ out0,
    const float* __restrict__ in1, unsigned short* __restrict__ out1, int n4) {
  int i = blockIdx.x * 256 + threadIdx.x;
  const float* in = in0;
  unsigned short* out = out0;
  if (i >= n4) { i -= n4; in = in1; out = out1; }
  float4 v = ((const float4*)in)[i];
  ushort4 o;
  o.x = f2bf(v.x); o.y = f2bf(v.y); o.z = f2bf(v.z); o.w = f2bf(v.w);
  ((ushort4*)out)[i] = o;
}

// ---------------- transpose + convert, z selects among 3 (K,N)->(N,K) ----------------
__global__ __launch_bounds__(256) void k_transpose3(
    const float* __restrict__ s0, unsigned short* __restrict__ d0,
    const float* __restrict__ s1, unsigned short* __restrict__ d1,
    const float* __restrict__ s2, unsigned short* __restrict__ d2,
    int K, int N) {
  const float* src = blockIdx.z == 0 ? s0 : (blockIdx.z == 1 ? s1 : s2);
  unsigned short* dst = blockIdx.z == 0 ? d0 : (blockIdx.z == 1 ? d1 : d2);
  __shared__ float tile[32][33];
  int n0 = blockIdx.x * 32, k0 = blockIdx.y * 32;
  int tx = threadIdx.x, ty = threadIdx.y;  // (32,8)
#pragma unroll
  for (int i = 0; i < 4; i++) {
    int r = ty + i * 8;
    if (k0 + r < K && n0 + tx < N) tile[r][tx] = src[(size_t)(k0 + r) * N + n0 + tx];
  }
  __syncthreads();
#pragma unroll
  for (int i = 0; i < 4; i++) {
    int rn = ty + i * 8;
    if (n0 + rn < N && k0 + tx < K)
      dst[(size_t)(n0 + rn) * K + k0 + tx] = f2bf(tile[tx][rn]);
  }
}

__global__ __launch_bounds__(256) void k_transpose2(
    const float* __restrict__ s0, unsigned short* __restrict__ d0,
    const float* __restrict__ s1, unsigned short* __restrict__ d1,
    int K, int N) {
  const float* src = blockIdx.z == 0 ? s0 : s1;
  unsigned short* dst = blockIdx.z == 0 ? d0 : d1;
  __shared__ float tile[32][33];
  int n0 = blockIdx.x * 32, k0 = blockIdx.y * 32;
  int tx = threadIdx.x, ty = threadIdx.y;
#pragma unroll
  for (int i = 0; i < 4; i++) {
    int r = ty + i * 8;
    if (k0 + r < K && n0 + tx < N) tile[r][tx] = src[(size_t)(k0 + r) * N + n0 + tx];
  }
  __syncthreads();
#pragma unroll
  for (int i = 0; i < 4; i++) {
    int rn = ty + i * 8;
    if (n0 + rn < N && k0 + tx < K)
      dst[(size_t)(n0 + rn) * K + k0 + tx] = f2bf(tile[tx][rn]);
  }
}

// ---------------- 256x256 bf16 GEMM, BK=32, dbuf + counted vmcnt, 2-phase ------
// Per iteration (NT = K/32):
//   vmcnt(4) [tile it landed; it+1 in flight] ; s_barrier
//   issue ds_read G0 (av0-3 + bv0-3, 8xb128) then G1 (av4-7, 4xb128)
//   lgkmcnt(4) -> G0 landed ; setprio ; 16 MFMA (i=0..3)   [G1 completes under]
//   lgkmcnt(0) ; s_barrier [buf consumed] ; stage tile it+2 (4 x gll16)
//   setprio ; 16 MFMA (i=4..7)
// Swizzle: granule slot = ((r&1)*4 + oct) ^ ((r>>1)&7) — verified 0-conflict.
__global__ __launch_bounds__(512, 2) void k_gemm256(
    const unsigned short* __restrict__ A, const unsigned short* __restrict__ Aalt,
    int asplit,
    const unsigned short* __restrict__ BTa, const unsigned short* __restrict__ BTb,
    int bstride, int bshift,
    unsigned short* __restrict__ Cbf, unsigned short* __restrict__ Calt,
    float* __restrict__ Cf, const unsigned short* __restrict__ Res,
    int N, int K, int ntiles) {
  __shared__ unsigned short lds[32768];  // 2 bufs x (A 8192 + B 8192 shorts) = 64KB
  int t = threadIdx.x;
  // XCD-chunked swizzle: consecutive logical tiles land on one XCD's L2.
  int lid = (blockIdx.x & 7) * ((int)gridDim.x >> 3) + (blockIdx.x >> 3);
  int mt = lid / ntiles, nt = lid - mt * ntiles;
  const unsigned short* BT = BTa;
  unsigned short* Cb = Cbf;
  if (mt >= asplit) { mt -= asplit; A = Aalt; BT = BTb; Cb = Calt; }
  if (bstride) BT += (size_t)(mt >> bshift) * (size_t)bstride;
  int m0 = mt * 256, n0 = nt * 256;
  int lane = t & 63, w = t >> 6;
  int wr = (w >> 2) * 128;   // wave row base within A tile (2 M-waves)
  int wc = (w & 3) * 64;     // wave col base within B tile (4 N-waves)
  int mq = lane & 15, q = lane >> 4;

  f32x4 zero = {0.f, 0.f, 0.f, 0.f};
  f32x4 acc[8][4];
#pragma unroll
  for (int i = 0; i < 8; i++)
#pragma unroll
    for (int j = 0; j < 4; j++) acc[i][j] = zero;

  // staging: granule g = t + p*512 in [0,1024): row2 = g>>3, slot = g&7,
  // pre = slot ^ (row2&7) -> global (r = row2*2 + (pre>>2), oct = pre&3).
  const unsigned short* gA[2];
  const unsigned short* gB[2];
  int oA[2], oB[2];
#pragma unroll
  for (int p = 0; p < 2; p++) {
    int g = t + p * 512;
    int row2 = g >> 3, pre = (g & 7) ^ (row2 & 7);
    int r = row2 * 2 + (pre >> 2), oct = pre & 3;
    gA[p] = A + (size_t)(m0 + r) * K + oct * 8;
    gB[p] = BT + (size_t)(n0 + r) * K + oct * 8;
    oA[p] = g * 8;
    oB[p] = 8192 + g * 8;
  }

  // fragment read addressing: slot = ((mq&1)*4 + q) ^ ((mq>>1)&7), row2 varies.
  int sA8 = ((((mq & 1) << 2) | q) ^ (mq >> 1)) * 8;
  int ra = (wr >> 1) + (mq >> 1);
  int rb = (wc >> 1) + (mq >> 1);

  int NT = K >> 5;  // 32 for K=1024
  // prologue: stage tiles 0 (buf0) and 1 (buf1) — 8 loads outstanding
#pragma unroll
  for (int p = 0; p < 2; p++) gll16(gA[p], &lds[oA[p]]);
#pragma unroll
  for (int p = 0; p < 2; p++) gll16(gB[p], &lds[oB[p]]);
#pragma unroll
  for (int p = 0; p < 2; p++) gll16(gA[p] + 32, &lds[16384 + oA[p]]);
#pragma unroll
  for (int p = 0; p < 2; p++) gll16(gB[p] + 32, &lds[16384 + oB[p]]);

  for (int it = 0; it < NT; ++it) {
    int lbase = (it & 1) << 14;  // cur*16384
    if (it < NT - 1) {
      asm volatile("s_waitcnt vmcnt(4)" ::: "memory");
    } else {
      asm volatile("s_waitcnt vmcnt(0)" ::: "memory");
    }
    __builtin_amdgcn_s_barrier();
    __builtin_amdgcn_sched_barrier(0);

    const unsigned short* la = &lds[lbase];
    const unsigned short* lb = &lds[lbase + 8192];
    bf16x8 av[8], bv[4];
    // G0: av[0..3] + bv[0..3] (8 x ds_read_b128)
#pragma unroll
    for (int i = 0; i < 4; i++)
      av[i] = *(const bf16x8*)&la[(ra + i * 8) * 64 + sA8];
#pragma unroll
    for (int j = 0; j < 4; j++)
      bv[j] = *(const bf16x8*)&lb[(rb + j * 8) * 64 + sA8];
    __builtin_amdgcn_sched_barrier(0);
    // G1: av[4..7] (4 x ds_read_b128)
#pragma unroll
    for (int i = 4; i < 8; i++)
      av[i] = *(const bf16x8*)&la[(ra + i * 8) * 64 + sA8];
    __builtin_amdgcn_sched_barrier(0);

    asm volatile("s_waitcnt lgkmcnt(4)" ::: "memory");  // G0 landed, G1 in flight
    __builtin_amdgcn_sched_barrier(0);
    __builtin_amdgcn_s_setprio(1);
#pragma unroll
    for (int i = 0; i < 4; i++)
#pragma unroll
      for (int j = 0; j < 4; j++)
        acc[i][j] = __builtin_amdgcn_mfma_f32_16x16x32_bf16(av[i], bv[j], acc[i][j], 0, 0, 0);
    __builtin_amdgcn_s_setprio(0);
    __builtin_amdgcn_sched_barrier(0);

    asm volatile("s_waitcnt lgkmcnt(0)" ::: "memory");  // all reads of buf done
    __builtin_amdgcn_sched_barrier(0);
    __builtin_amdgcn_s_barrier();     // buf[cur] fully consumed by all waves
    __builtin_amdgcn_sched_barrier(0);

    if (it + 2 < NT) {                // stage tile it+2 into buf[cur]
      int k0 = (it + 2) * 32;
#pragma unroll
      for (int p = 0; p < 2; p++) gll16(gA[p] + k0, &lds[lbase + oA[p]]);
#pragma unroll
      for (int p = 0; p < 2; p++) gll16(gB[p] + k0, &lds[lbase + oB[p]]);
    }

    __builtin_amdgcn_s_setprio(1);
#pragma unroll
    for (int i = 4; i < 8; i++)
#pragma unroll
      for (int j = 0; j < 4; j++)
        acc[i][j] = __builtin_amdgcn_mfma_f32_16x16x32_bf16(av[i], bv[j], acc[i][j], 0, 0, 0);
    __builtin_amdgcn_s_setprio(0);
  }

#pragma unroll
  for (int i = 0; i < 8; i++)
#pragma unroll
    for (int j = 0; j < 4; j++)
#pragma unroll
      for (int r = 0; r < 4; r++) {
        int row = m0 + wr + i * 16 + q * 4 + r;
        int col = n0 + wc + j * 16 + mq;
        size_t o = (size_t)row * N + col;
        float v = acc[i][j][r];
        if (Res) v += bf2f(Res[o]);
        if (Cf) Cf[o] = v;
        if (Cb) Cb[o] = f2bf(v);
      }
}

// ---------------- skinny GEMM N=16: logits with scale+mask (64 rows/block) ----------------
__global__ __launch_bounds__(256) void k_logits16(
    const unsigned short* __restrict__ A,      // (B*S, K) bf16
    const unsigned short* __restrict__ BT16,   // (16, K) bf16
    const float* __restrict__ mask,            // (B*S) f32
    float* __restrict__ outl,                  // (B,16,S) f32
    int K) {
  __shared__ unsigned short lA[64 * 32];
  int t = threadIdx.x;
  int m0 = blockIdx.x * 64;
  int lane = t & 63, w = t >> 6;
  int mq = lane & 15, q = lane >> 4;
  f32x4 acc = {0.f, 0.f, 0.f, 0.f};
  const unsigned short* gA = A + (size_t)(m0 + (t >> 2)) * K + (t & 3) * 8;
  unsigned short* pA = &lA[t * 8];
  for (int k0 = 0; k0 < K; k0 += 32) {
    gll16(gA + k0, pA);
    bf16x8 bv = *(const bf16x8*)&BT16[(size_t)mq * K + k0 + q * 8];
    __syncthreads();
    bf16x8 a0 = *(const bf16x8*)&lA[(w * 16 + mq) * 32 + q * 8];
    acc = __builtin_amdgcn_mfma_f32_16x16x32_bf16(a0, bv, acc, 0, 0, 0);
    __syncthreads();
  }
#pragma unroll
  for (int r = 0; r < 4; r++) {
    int row = m0 + w * 16 + q * 4 + r;
    int b = row >> 11, s = row & 2047;
    float v = acc[r] * SCALE_ - (1.0f - mask[row]) * BIGNEG_;
    outl[((size_t)(b * 16 + mq)) * 2048 + s] = v;
  }
}

// ---------------- k-logits with fused head-mixing gather + gq-scaled B (64 rows/block) ----------------
__global__ __launch_bounds__(256) void k_logits16g(
    const unsigned short* __restrict__ Khbf,   // (B,2048,1024) bf16
    const unsigned short* __restrict__ WkT,    // (16,1024) bf16
    const float* __restrict__ gq,              // (B,1024) f32
    const float* __restrict__ mask,            // (B*S) f32
    float* __restrict__ outl) {                // (B,16,S) f32
  __shared__ unsigned short lA[64 * 32];
  int t = threadIdx.x;
  int m0 = blockIdx.x * 64;
  int bb = m0 >> 11;
  int h2 = (m0 >> 7) & 15;
  int half = (m0 >> 6) & 1;
  int lane = t & 63, w = t >> 6;
  int mq = lane & 15, q = lane >> 4;
  f32x4 acc = {0.f, 0.f, 0.f, 0.f};
  int r0 = half * 64 + (t >> 2);
  int c0 = t & 3;
  const unsigned short* base = Khbf + (size_t)bb * 2048 * 1024 + h2 * 64;
  const float* gqb = gq + bb * 1024 + h2 * 64;
  unsigned short* pA = &lA[t * 8];
  for (int k0 = 0; k0 < 1024; k0 += 32) {
    int kc0 = k0 + c0 * 8;
    gll16(base + (size_t)(16 * r0 + (kc0 >> 6)) * 1024 + (kc0 & 63), pA);
    int kq = k0 + q * 8;
    bf16x8 wv = *(const bf16x8*)&WkT[(size_t)mq * 1024 + kq];
    float4 g0 = *(const float4*)&gqb[kq & 63];
    float4 g1 = *(const float4*)&gqb[(kq & 63) + 4];
    bf16x8 bv;
    bv[0] = (__bf16)((float)wv[0] * g0.x);
    bv[1] = (__bf16)((float)wv[1] * g0.y);
    bv[2] = (__bf16)((float)wv[2] * g0.z);
    bv[3] = (__bf16)((float)wv[3] * g0.w);
    bv[4] = (__bf16)((float)wv[4] * g1.x);
    bv[5] = (__bf16)((float)wv[5] * g1.y);
    bv[6] = (__bf16)((float)wv[6] * g1.z);
    bv[7] = (__bf16)((float)wv[7] * g1.w);
    __syncthreads();
    bf16x8 a0 = *(const bf16x8*)&lA[(w * 16 + mq) * 32 + q * 8];
    acc = __builtin_amdgcn_mfma_f32_16x16x32_bf16(a0, bv, acc, 0, 0, 0);
    __syncthreads();
  }
#pragma unroll
  for (int r = 0; r < 4; r++) {
    int row = m0 + w * 16 + q * 4 + r;
    int b = row >> 11, s = row & 2047;
    float v = acc[r] * SCALE_ - (1.0f - mask[row]) * BIGNEG_;
    outl[((size_t)(b * 16 + mq)) * 2048 + s] = v;
  }
}

// ---------------- in-place softmax over rows of 2048 ----------------
__global__ __launch_bounds__(256) void k_softmax(float* __restrict__ logits) {
  __shared__ float red[8];
  int t = threadIdx.x;
  int lane = t & 63, w = t >> 6;
  float* lg = logits + (size_t)blockIdx.x * 2048;
  float4 a = ((const float4*)lg)[t];
  float4 b = ((const float4*)lg)[t + 256];
  float mx = fmaxf(fmaxf(fmaxf(a.x, a.y), fmaxf(a.z, a.w)),
                   fmaxf(fmaxf(b.x, b.y), fmaxf(b.z, b.w)));
#pragma unroll
  for (int off = 32; off > 0; off >>= 1) mx = fmaxf(mx, __shfl_down(mx, off, 64));
  if (lane == 0) red[w] = mx;
  __syncthreads();
  mx = fmaxf(fmaxf(red[0], red[1]), fmaxf(red[2], red[3]));
  float4 ea, eb;
  ea.x = expf(a.x - mx); ea.y = expf(a.y - mx); ea.z = expf(a.z - mx); ea.w = expf(a.w - mx);
  eb.x = expf(b.x - mx); eb.y = expf(b.y - mx); eb.z = expf(b.z - mx); eb.w = expf(b.w - mx);
  float ps = ea.x + ea.y + ea.z + ea.w + eb.x + eb.y + eb.z + eb.w;
#pragma unroll
  for (int off = 32; off > 0; off >>= 1) ps += __shfl_down(ps, off, 64);
  if (lane == 0) red[4 + w] = ps;
  __syncthreads();
  float inv = 1.0f / (red[4] + red[5] + red[6] + red[7]);
  ea.x *= inv; ea.y *= inv; ea.z *= inv; ea.w *= inv;
  eb.x *= inv; eb.y *= inv; eb.z *= inv; eb.w *= inv;
  ((float4*)lg)[t] = ea;
  ((float4*)lg)[t + 256] = eb;
}

// ---------------- chunked weighted pool, stage 1 ----------------
__global__ __launch_bounds__(256) void k_poolpart(
    const float* __restrict__ att,             // (B,16,2048) softmaxed
    const unsigned short* __restrict__ X,      // (B,2048,1024) bf16
    float* __restrict__ partial) {             // (B,64,1024) f32
  __shared__ float satt[32 * 16];
  int c = blockIdx.x, b = blockIdx.y;
  int t = threadIdx.x;
  for (int i = t; i < 512; i += 256) {
    int sl = i >> 4, h = i & 15;
    satt[i] = att[(((size_t)b * 16 + h) << 11) + c * 32 + sl];
  }
  __syncthreads();
  int h = t >> 4;
  const ushort4* xp = (const ushort4*)X + ((size_t)b * 2048 + c * 32) * 256 + t;
  float4 acc = {0.f, 0.f, 0.f, 0.f};
#pragma unroll 8
  for (int sl = 0; sl < 32; sl++) {
    float av = satt[sl * 16 + h];
    ushort4 xv = xp[sl * 256];
    acc.x += av * bf2f(xv.x);
    acc.y += av * bf2f(xv.y);
    acc.z += av * bf2f(xv.z);
    acc.w += av * bf2f(xv.w);
  }
  ((float4*)partial)[((size_t)b * 64 + c) * 256 + t] = acc;
}

// ---------------- chunked weighted pool, stage 2 ----------------
__global__ __launch_bounds__(256) void k_poolfin(
    const float* __restrict__ partial,         // (B,64,1024)
    const float* __restrict__ gmul,            // null or (B,1024)
    float* __restrict__ outp) {                // (B,1024)
  int oi = blockIdx.x * 256 + threadIdx.x;
  int b = oi >> 10;
  const float* pp = partial + (size_t)b * 64 * 1024 + (oi & 1023);
  float s = 0.f;
#pragma unroll 8
  for (int c = 0; c < 64; c++) s += pp[(size_t)c * 1024];
  if (gmul) s *= gmul[oi];
  outp[oi] = s;
}

// ---------------- WPb[b][n][k] = WPT[n][k] * gk[b][k] ----------------
__global__ __launch_bounds__(256) void k_wpb(
    const unsigned short* __restrict__ WPT,    // (1024,1024) bf16, N-major
    const float* __restrict__ gk,              // (B,1024)
    unsigned short* __restrict__ WPb) {        // (B,1024,1024) bf16
  int i = blockIdx.x * 256 + threadIdx.x;
  int flat4 = i * 4;
  int b = flat4 >> 20;
  int rem = flat4 & 1048575;
  int k = rem & 1023;
  ushort4 wv = *(const ushort4*)&WPT[rem];
  float4 gv = *(const float4*)&gk[b * 1024 + k];
  ushort4 o;
  o.x = f2bf(bf2f(wv.x) * gv.x);
  o.y = f2bf(bf2f(wv.y) * gv.y);
  o.z = f2bf(bf2f(wv.z) * gv.z);
  o.w = f2bf(bf2f(wv.w) * gv.w);
  *(ushort4*)&WPb[flat4] = o;
}

extern "C" void kernel_launch(void* const* d_in, const int* in_sizes, int n_in,
                              void* d_out, int out_size, void* d_ws, size_t ws_size,
                              hipStream_t stream) {
  const float* Qseq  = (const float*)d_in[0];
  const float* Kseq  = (const float*)d_in[1];
  const float* Qmask = (const float*)d_in[2];
  const float* Kmask = (const float*)d_in[3];
  const float* WQ    = (const float*)d_in[4];
  const float* WK    = (const float*)d_in[5];
  const float* Wq    = (const float*)d_in[6];
  const float* Wk    = (const float*)d_in[7];
  const float* WP    = (const float*)d_in[8];
  float* out = (float*)d_out;

  const size_t SD = (size_t)B_ * S_ * D_;  // 16,777,216
  unsigned short* Qbf  = (unsigned short*)d_ws;
  unsigned short* Khbf = Qbf + SD;
  unsigned short* buf0 = Khbf + SD;           // Q conv staging; later partial(2MB)+WPb(16MB)
  unsigned short* WQT  = buf0 + SD;
  unsigned short* WKT  = WQT + (size_t)D_ * D_;
  unsigned short* WPT  = WKT + (size_t)D_ * D_;
  unsigned short* WqT  = WPT + (size_t)D_ * D_;
  unsigned short* WkT  = WqT + (size_t)H_ * D_;
  float* ql = (float*)(WkT + (size_t)H_ * D_);
  float* kl = ql + (size_t)B_ * H_ * S_;
  float* gq = kl + (size_t)B_ * H_ * S_;
  float* gk = gq + (size_t)B_ * D_;
  float* partial = (float*)buf0;                            // 2 MB
  unsigned short* WPb = buf0 + 2 * 1024 * 1024;             // 16 MB
  unsigned short* Kstage = (unsigned short*)d_out;          // 32 MB of the 64 MB f32 out buffer

  dim3 blk256(256);
  dim3 blk512(512);
  dim3 tblk(32, 8);
  int n4 = (int)(SD / 4);

  // weight conversions
  k_transpose3<<<dim3(32, 32, 3), tblk, 0, stream>>>(WQ, WQT, WK, WKT, WP, WPT, D_, D_);
  k_transpose2<<<dim3(1, 32, 2), tblk, 0, stream>>>(Wq, WqT, Wk, WkT, D_, H_);

  // convert both activations in one dispatch
  k_conv2<<<dim3(2 * ((n4 + 255) / 256)), blk256, 0, stream>>>(Qseq, buf0, Kseq, Kstage, n4);

  // fused GEMM1+GEMM2: Qbf = Qstage@WQ ; Khbf = Kstage@WK   (64 mtiles per half, 4 ntiles)
  k_gemm256<<<dim3(512), blk512, 0, stream>>>(buf0, Kstage, 64, WQT, WKT, 0, 0,
                                              Qbf, Khbf, (float*)nullptr,
                                              (const unsigned short*)nullptr, D_, D_, 4);

  // q attention -> gq
  k_logits16<<<dim3(256), blk256, 0, stream>>>(Qbf, WqT, Qmask, ql, D_);
  k_softmax<<<dim3(128), blk256, 0, stream>>>(ql);
  k_poolpart<<<dim3(64, 8), blk256, 0, stream>>>(ql, Qbf, partial);
  k_poolfin<<<dim3(32), blk256, 0, stream>>>(partial, (const float*)nullptr, gq);

  // k attention (fused gather over head-mixed QK_flat) -> gk
  k_logits16g<<<dim3(256), blk256, 0, stream>>>(Khbf, WkT, gq, Kmask, kl);
  k_softmax<<<dim3(128), blk256, 0, stream>>>(kl);
  k_poolpart<<<dim3(64, 8), blk256, 0, stream>>>(kl, Khbf, partial);
  k_poolfin<<<dim3(32), blk256, 0, stream>>>(partial, gq, gk);

  // final: out = Qbf @ (WP .* gk[b]) + Qbf   (overwrites Kstage region — no longer read)
  k_wpb<<<dim3(8192), blk256, 0, stream>>>(WPT, gk, WPb);
  k_gemm256<<<dim3(256), blk512, 0, stream>>>(Qbf, Qbf, 1 << 30, WPb, WPb, 1 << 20, 3,
                                              (unsigned short*)nullptr, (unsigned short*)nullptr,
                                              out, Qbf, D_, D_, 4);
}